// Round 8
// baseline (273.659 us; speedup 1.0000x reference)
//
#include <hip/hip_runtime.h>
#include <hip/hip_bf16.h>

// (B, LIN, E, D, N) = (32, 2048, 512, 512, 2)
#define L_SZ 2048
#define E_SZ 512
#define D_SZ 512
#define ND   1024
// ws layout: dec_proj (32*512 f32) | Bt (512*512 bf16, [n][k]) | scores (32*2048 f32)
#define WS_DEC_OFF 0
#define WS_BT_OFF  (32*512*4)
#define WS_SC_OFF  (32*512*4 + 512*512*2)

typedef unsigned short ushort_t;
typedef unsigned int   uint_t;
typedef __attribute__((ext_vector_type(8))) short short8;   // 8 bf16 (MFMA A/B frag)
typedef __attribute__((ext_vector_type(4))) float floatx4;  // MFMA C/D frag

__device__ __forceinline__ ushort_t f2bf(float f) {
  uint_t u = __builtin_bit_cast(uint_t, f);
  u += 0x7fffu + ((u >> 16) & 1u);
  return (ushort_t)(u >> 16);
}

__device__ __forceinline__ float fast_tanh(float x) {
  float e = __expf(2.0f * x);
  return 1.0f - 2.0f * __builtin_amdgcn_rcpf(e + 1.0f);
}

// ---------------------------------------------------------------------------
// Prep, 512 blocks:
//  blocks 0..255  : dec_proj[b][d] (b=blk>>3, d-tile=blk&7), k split 4-way + LDS reduce
//  blocks 256..511: Bt[n][k] = bf16(W1[1024+k][n]) via 32x32 LDS transpose tiles
// ---------------------------------------------------------------------------
__global__ __launch_bounds__(256) void prep_k(const float* __restrict__ dh,
                                              const float* __restrict__ W1,
                                              const float* __restrict__ b1,
                                              float* __restrict__ dec,
                                              ushort_t* __restrict__ Bt) {
  int blk = blockIdx.x, t = threadIdx.x;
  if (blk < 256) {
    int b = blk >> 3, d = (blk & 7) * 64 + (t & 63);
    int q = t >> 6;
    __shared__ float red[4][64];
    const float* dfb = dh + b * ND;
    float s = 0.f;
    #pragma unroll 8
    for (int k = q * 256; k < q * 256 + 256; k++)
      s = fmaf(dfb[k], W1[k * D_SZ + d], s);
    red[q][t & 63] = s;
    __syncthreads();
    if (q == 0)
      dec[b * D_SZ + d] = red[0][t] + red[1][t] + red[2][t] + red[3][t] + b1[d];
  } else {
    int tid = blk - 256;
    int tk = (tid >> 4) * 32, tn = (tid & 15) * 32;
    __shared__ float tile[32][33];
    int cc = t & 31, r8 = t >> 5;
    #pragma unroll
    for (int p = 0; p < 4; p++) {
      int r = r8 + p * 8;
      tile[r][cc] = W1[(ND + tk + r) * D_SZ + tn + cc];
    }
    __syncthreads();
    #pragma unroll
    for (int p = 0; p < 4; p++) {
      int nn = r8 + p * 8;
      Bt[(tn + nn) * E_SZ + tk + cc] = f2bf(tile[cc][nn]);
    }
  }
}

// ---------------------------------------------------------------------------
// Main (round 8): BARRIER-FREE K-loop. Diagnosis r0-r7: the only config that
// broke 88us was r0's 2-independent-blocks/CU; all barrier-locked single-group
// schedules (r2/r5/r6/r7) land 88-101us regardless of traffic, vmcnt style,
// or occupancy. So: eliminate K-loop barriers entirely.
//   1. A (enc tile, 64 rows) staged ONCE full-K in LDS (64 KB), cell layout
//      (kw,mt,quad,col) -> every frag ds_read_b128 is a contiguous 1KB wave
//      read (zero conflicts); cross-wave same-address reads broadcast.
//      ONE __syncthreads after the prologue; none afterwards.
//   2. B frags read straight L2->VGPR (4 x short8 per window), b0/b1
//      double-phase regs, prefetched 1 window ahead (static indexing).
//      Compiler emits its own counted vmcnt; window >> L2 latency.
//   3. LDS 64.3 KB -> 2 blocks/CU; launch_bounds(512,4) caps regs at 128
//      (acc 64 AGPR + ~60 VGPR) -> 16 independent waves/CU, each self-paced.
// BK=32, 16 windows, 16 MFMA/window/wave. Grid (32,32) = 1024 blocks.
// ---------------------------------------------------------------------------
__global__ __launch_bounds__(512, 4) void main_k(const float* __restrict__ enc,
                                                 const ushort_t* __restrict__ Bt,
                                                 const float* __restrict__ dec,
                                                 const float* __restrict__ w2,
                                                 float* __restrict__ scores) {
  const int b  = blockIdx.y;
  const int l0 = blockIdx.x * 64;
  const int t  = threadIdx.x;            // 0..511
  const int wave = t >> 6, lane = t & 63;
  const int col = lane & 15, quad = lane >> 4;

  // A cells: cell(kw,mt,quad,col) at ushort index cell*8; 4096 cells = 64 KB.
  __shared__ __align__(16) ushort_t As[64 * 512];
  __shared__ float s_sc[64];

  if (t < 64) s_sc[t] = 0.f;

  floatx4 acc[4][4];
  #pragma unroll
  for (int mt = 0; mt < 4; mt++)
    #pragma unroll
    for (int nt = 0; nt < 4; nt++)
      acc[mt][nt] = (floatx4){0.f, 0.f, 0.f, 0.f};

  const float* arow = enc + (size_t)(b * L_SZ + l0) * E_SZ;

  // ---- prologue: stage A full-K into LDS (once). Thread t does 8 cells
  // c = t + j*512; decode kw=c>>8, mt=(c>>6)&3, q=(c>>4)&3, cl=c&15;
  // cell holds A[row=mt*16+cl][k = kw*32+q*8 .. +8] as bf16.
  // Global pattern per wave-instr: rows in 128B-contiguous spans (coalesced).
  #pragma unroll
  for (int j = 0; j < 8; j++) {
    int c = t + j * 512;
    int kw = c >> 8, mt = (c >> 6) & 3, q = (c >> 4) & 3, cl = c & 15;
    const float* gp = arow + (mt * 16 + cl) * E_SZ + kw * 32 + q * 8;
    float4 f0 = *(const float4*)gp;
    float4 f1 = *(const float4*)(gp + 4);
    union { short8 v; __hip_bfloat162 h[4]; } pk;
    pk.h[0] = __float22bfloat162_rn(make_float2(f0.x, f0.y));
    pk.h[1] = __float22bfloat162_rn(make_float2(f0.z, f0.w));
    pk.h[2] = __float22bfloat162_rn(make_float2(f1.x, f1.y));
    pk.h[3] = __float22bfloat162_rn(make_float2(f1.z, f1.w));
    *(short8*)&As[c * 8] = pk.v;
  }
  __syncthreads();   // the ONLY barrier before the epilogue

  // B frag bases: lane (col,quad), frag nt reads Bt[n = wave*64+nt*16+col]
  // [k = kw*32 + quad*8 .. +8]; per-window advance = 32 ushorts (64B imm).
  const ushort_t* bb0 = Bt + (wave * 64 +  0 + col) * E_SZ + quad * 8;
  const ushort_t* bb1 = Bt + (wave * 64 + 16 + col) * E_SZ + quad * 8;
  const ushort_t* bb2 = Bt + (wave * 64 + 32 + col) * E_SZ + quad * 8;
  const ushort_t* bb3 = Bt + (wave * 64 + 48 + col) * E_SZ + quad * 8;

  short8 b0[4], b1[4];
  b0[0] = *(const short8*)bb0;
  b0[1] = *(const short8*)bb1;
  b0[2] = *(const short8*)bb2;
  b0[3] = *(const short8*)bb3;

  #pragma unroll 1
  for (int kw2 = 0; kw2 < 16; kw2 += 2) {
    // ---- even window kw2: consume b0, prefetch kw2+1 into b1 ----
    {
      const int off = (kw2 + 1) * 32;
      b1[0] = *(const short8*)(bb0 + off);
      b1[1] = *(const short8*)(bb1 + off);
      b1[2] = *(const short8*)(bb2 + off);
      b1[3] = *(const short8*)(bb3 + off);
      #pragma unroll
      for (int mt = 0; mt < 4; mt++) {
        short8 af = *(const short8*)&As[(kw2 * 256 + mt * 64 + quad * 16 + col) * 8];
        #pragma unroll
        for (int nt = 0; nt < 4; nt++)
          acc[mt][nt] = __builtin_amdgcn_mfma_f32_16x16x32_bf16(af, b0[nt], acc[mt][nt], 0, 0, 0);
      }
    }
    // ---- odd window kw2+1: consume b1, prefetch kw2+2 into b0 ----
    {
      if (kw2 < 14) {
        const int off = (kw2 + 2) * 32;
        b0[0] = *(const short8*)(bb0 + off);
        b0[1] = *(const short8*)(bb1 + off);
        b0[2] = *(const short8*)(bb2 + off);
        b0[3] = *(const short8*)(bb3 + off);
      }
      #pragma unroll
      for (int mt = 0; mt < 4; mt++) {
        short8 af = *(const short8*)&As[((kw2 + 1) * 256 + mt * 64 + quad * 16 + col) * 8];
        #pragma unroll
        for (int nt = 0; nt < 4; nt++)
          acc[mt][nt] = __builtin_amdgcn_mfma_f32_16x16x32_bf16(af, b1[nt], acc[mt][nt], 0, 0, 0);
      }
    }
  }

  // ---- epilogue: tanh(acc + dec) . w2, reduced over n ----
  // C/D: D[row=quad*4+r][col] => m = mt*16+quad*4+r, n = wave*64+nt*16+col
  const float* decb = dec + b * D_SZ;
  float sums[4][4];
  #pragma unroll
  for (int mt = 0; mt < 4; mt++)
    #pragma unroll
    for (int r = 0; r < 4; r++) sums[mt][r] = 0.f;

  #pragma unroll
  for (int nt = 0; nt < 4; nt++) {
    int n = wave * 64 + nt * 16 + col;
    float dv = decb[n];
    float wv = w2[n];
    #pragma unroll
    for (int mt = 0; mt < 4; mt++)
      #pragma unroll
      for (int r = 0; r < 4; r++)
        sums[mt][r] += fast_tanh(acc[mt][nt][r] + dv) * wv;
  }
  #pragma unroll
  for (int mt = 0; mt < 4; mt++) {
    #pragma unroll
    for (int r = 0; r < 4; r++) {
      float v = sums[mt][r];
      v += __shfl_xor(v, 1, 16);
      v += __shfl_xor(v, 2, 16);
      v += __shfl_xor(v, 4, 16);
      v += __shfl_xor(v, 8, 16);
      if (col == 0) atomicAdd(&s_sc[mt * 16 + quad * 4 + r], v);  // 8 waves/row
    }
  }
  __syncthreads();
  if (t < 64) scores[b * L_SZ + l0 + t] = s_sc[t];
}

// ---------------------------------------------------------------------------
// Softmax: one WG (1024 threads) per batch row of 2048.
// ---------------------------------------------------------------------------
__global__ __launch_bounds__(1024) void softmax_k(const float* __restrict__ sc,
                                                  float* __restrict__ out) {
  int b = blockIdx.x, t = threadIdx.x;
  int wave = t >> 6, lane = t & 63;
  __shared__ float redm[16], reds[16];
  const float* row = sc + b * L_SZ;
  float v0 = row[t], v1 = row[t + 1024];
  float mx = fmaxf(v0, v1);
  #pragma unroll
  for (int off = 32; off >= 1; off >>= 1) mx = fmaxf(mx, __shfl_xor(mx, off, 64));
  if (lane == 0) redm[wave] = mx;
  __syncthreads();
  float m = redm[0];
  #pragma unroll
  for (int i = 1; i < 16; i++) m = fmaxf(m, redm[i]);
  v0 = __expf(v0 - m);
  v1 = __expf(v1 - m);
  float s = v0 + v1;
  #pragma unroll
  for (int off = 32; off >= 1; off >>= 1) s += __shfl_xor(s, off, 64);
  if (lane == 0) reds[wave] = s;
  __syncthreads();
  float sum = reds[0];
  #pragma unroll
  for (int i = 1; i < 16; i++) sum += reds[i];
  float inv = 1.0f / sum;
  out[b * L_SZ + t]        = v0 * inv;
  out[b * L_SZ + t + 1024] = v1 * inv;
}

extern "C" void kernel_launch(void* const* d_in, const int* in_sizes, int n_in,
                              void* d_out, int out_size, void* d_ws, size_t ws_size,
                              hipStream_t stream) {
  const float* d_hidden = (const float*)d_in[0];   // (32, 2, 512)
  const float* enc      = (const float*)d_in[1];   // (32, 2048, 512)
  const float* W1       = (const float*)d_in[2];   // (1536, 512)
  const float* b1       = (const float*)d_in[3];   // (512,)
  const float* w2       = (const float*)d_in[4];   // (512,)
  float* out = (float*)d_out;                      // (32, 2048)

  char* ws = (char*)d_ws;
  float*    dec = (float*)(ws + WS_DEC_OFF);
  ushort_t* Bt  = (ushort_t*)(ws + WS_BT_OFF);
  float*    sc  = (float*)(ws + WS_SC_OFF);

  prep_k<<<512, 256, 0, stream>>>(d_hidden, W1, b1, dec, Bt);
  main_k<<<dim3(32, 32), 512, 0, stream>>>(enc, Bt, dec, w2, sc);
  softmax_k<<<32, 1024, 0, stream>>>(sc, out);
}